// Round 9
// baseline (262.009 us; speedup 1.0000x reference)
//
#include <hip/hip_runtime.h>
#include <math.h>

#define DIMC 256
#define NHEADS 8
#define HDIM 32
#define CPBH 512
#define BB 2
#define NSEQ 2304
#define TAB 9025
#define TABP 9040                  // padded table stride (16B-aligned rows)
#define RTOT (BB*NHEADS*NSEQ)      // 36864
#define SPLITS 4
#define MSP (NSEQ/SPLITS)          // 576 m per split
#define PBS 36                     // pbuf row stride in u16
#define NCHUNK (NSEQ/32)           // 72
#define LOG2E 1.44269504088896340736f

#define NX  (BB*NSEQ*DIMC)         // 1,179,648
#define NWQ (3*DIMC*DIMC)          // 196,608
#define NWP (DIMC*DIMC)            // 65,536

#define SPLIT_BLOCKS ((NX + NWQ + NWP) / 256)          // 5632
#define IDXP_ELEMS   (NSEQ * NCHUNK * 16)              // 2,654,208
#define IDXP_BLOCKS  (IDXP_ELEMS / 256)                // 10368
#define CPB_BLOCKS   ((TAB + 63) / 64)                 // 142

typedef unsigned short ushort;
typedef __attribute__((ext_vector_type(8))) short short8;
typedef __attribute__((ext_vector_type(4))) short short4v;
typedef __attribute__((ext_vector_type(4))) float f32x4;

#define MFMA16(a,b,c) __builtin_amdgcn_mfma_f32_16x16x32_bf16((a),(b),(c),0,0,0)

__device__ __forceinline__ ushort f2bf(float x) {          // RNE fp32->bf16
  unsigned u = __float_as_uint(x);
  u += 0x7FFFu + ((u >> 16) & 1u);
  return (ushort)(u >> 16);
}
__device__ __forceinline__ float bf2f(ushort b) {
  return __uint_as_float(((unsigned)b) << 16);
}
__device__ __forceinline__ float fexp2(float x) {
#if defined(__has_builtin)
#if __has_builtin(__builtin_amdgcn_exp2f)
  return __builtin_amdgcn_exp2f(x);
#else
  return exp2f(x);
#endif
#else
  return exp2f(x);
#endif
}
// pack trunc-bf16(p0) | trunc-bf16(p1)<<16 in one v_perm
__device__ __forceinline__ unsigned pack_trunc(float p0, float p1) {
  return __builtin_amdgcn_perm(__float_as_uint(p1), __float_as_uint(p0), 0x07060302u);
}

// ------- setup: CPB MLP (LDS-tiled, blocks FIRST) + split planes + idx pair-pack -------
__global__ void setup_kernel(const float* __restrict__ x, const float* __restrict__ wq,
                             const float* __restrict__ wp, const int* __restrict__ idx,
                             const float* __restrict__ tbl, const float* __restrict__ W1,
                             const float* __restrict__ b1, const float* __restrict__ W2,
                             const float* __restrict__ b2,
                             ushort* __restrict__ xh, ushort* __restrict__ xl,
                             ushort* __restrict__ wqh, ushort* __restrict__ wql,
                             ushort* __restrict__ wph, ushort* __restrict__ wpl,
                             unsigned* __restrict__ idxP, ushort* __restrict__ tabBf) {
  __shared__ float w1b[CPBH * 4];
  __shared__ float w2t[CPBH * NHEADS];
  __shared__ float part[4][64][NHEADS];
  int blk = blockIdx.x;
  int tid = threadIdx.x;
  if (blk < CPB_BLOCKS) {
    for (int i = tid; i < CPBH; i += 256) {
      w1b[i * 4 + 0] = W1[2 * i];
      w1b[i * 4 + 1] = W1[2 * i + 1];
      w1b[i * 4 + 2] = b1[i];
      w1b[i * 4 + 3] = 0.f;
    }
    for (int i = tid; i < CPBH * NHEADS; i += 256)
      w2t[(i & (CPBH - 1)) * NHEADS + (i >> 9)] = W2[i];
    int tl = tid & 63, jc = tid >> 6;
    int t = blk * 64 + tl;
    bool valid = t < TAB;
    float c0 = 0.f, c1 = 0.f;
    if (valid) { c0 = tbl[2 * t]; c1 = tbl[2 * t + 1]; }
    __syncthreads();
    float acc[NHEADS];
#pragma unroll
    for (int h = 0; h < NHEADS; ++h) acc[h] = 0.f;
    for (int j = jc * 128; j < jc * 128 + 128; ++j) {
      float4 wv = *(const float4*)&w1b[j * 4];
      float hid = fmaxf(fmaf(c0, wv.x, fmaf(c1, wv.y, wv.z)), 0.f);
      float4 wa = *(const float4*)&w2t[j * NHEADS];
      float4 wb = *(const float4*)&w2t[j * NHEADS + 4];
      acc[0] = fmaf(hid, wa.x, acc[0]);
      acc[1] = fmaf(hid, wa.y, acc[1]);
      acc[2] = fmaf(hid, wa.z, acc[2]);
      acc[3] = fmaf(hid, wa.w, acc[3]);
      acc[4] = fmaf(hid, wb.x, acc[4]);
      acc[5] = fmaf(hid, wb.y, acc[5]);
      acc[6] = fmaf(hid, wb.z, acc[6]);
      acc[7] = fmaf(hid, wb.w, acc[7]);
    }
#pragma unroll
    for (int h = 0; h < NHEADS; ++h) part[jc][tl][h] = acc[h];
    __syncthreads();
    if (jc == 0 && valid) {
#pragma unroll
      for (int h = 0; h < NHEADS; ++h) {
        float s = part[0][tl][h] + part[1][tl][h] + part[2][tl][h] + part[3][tl][h] + b2[h];
        tabBf[h * TABP + t] = f2bf(s * LOG2E);   // bias pre-scaled by log2(e)
      }
    }
  } else if (blk < CPB_BLOCKS + SPLIT_BLOCKS) {
    int i = (blk - CPB_BLOCKS) * 256 + tid;
    const float* src; ushort *hi, *lo; int j;
    if (i < NX)            { src = x;  hi = xh;  lo = xl;  j = i; }
    else if (i < NX + NWQ) { src = wq; hi = wqh; lo = wql; j = i - NX; }
    else                   { src = wp; hi = wph; lo = wpl; j = i - NX - NWQ; }
    float v = src[j];
    ushort h = f2bf(v);
    hi[j] = h;
    lo[j] = f2bf(v - bf2f(h));
  } else {
    int e = (blk - CPB_BLOCKS - SPLIT_BLOCKS) * 256 + tid;
    int cc = e & 15; int ch = (e >> 4) % NCHUNK; int n = e / (16 * NCHUNK);
    int mbase = ch * 32 + cc;
    unsigned lo = (unsigned)idx[(size_t)n * NSEQ + mbase];
    unsigned hi = (unsigned)idx[(size_t)n * NSEQ + mbase + 16];
    idxP[e] = lo | (hi << 16);
  }
}

// ------- fused QKV GEMM + norm/scale/split + V transpose -------
__launch_bounds__(256)
__global__ void gemm_qkv(const ushort* __restrict__ Ah, const ushort* __restrict__ Al,
                         const ushort* __restrict__ Bh, const ushort* __restrict__ Bl,
                         const float* __restrict__ bias, const float* __restrict__ temp,
                         const float* __restrict__ sls, const float* __restrict__ qe,
                         ushort* __restrict__ qhi, ushort* __restrict__ qlo,
                         ushort* __restrict__ khi, ushort* __restrict__ klo,
                         ushort* __restrict__ vT) {
  __shared__ float vbuf[64][65];
  int tid = threadIdx.x;
  int lane = tid & 63, w = tid >> 6;
  int g = lane >> 4, c = lane & 15;
  int n0 = blockIdx.x * 64, m0 = blockIdx.y * 64;
  int mw = m0 + w * 16;
  const int K = DIMC;
  f32x4 acc[4] = {{0,0,0,0},{0,0,0,0},{0,0,0,0},{0,0,0,0}};
#pragma unroll 2
  for (int k0 = 0; k0 < K; k0 += 32) {
    short8 ah = *(const short8*)&Ah[(size_t)(mw + c) * K + k0 + g * 8];
    short8 al = *(const short8*)&Al[(size_t)(mw + c) * K + k0 + g * 8];
#pragma unroll
    for (int nt = 0; nt < 4; ++nt) {
      short8 bh = *(const short8*)&Bh[(size_t)(n0 + nt * 16 + c) * K + k0 + g * 8];
      short8 bl = *(const short8*)&Bl[(size_t)(n0 + nt * 16 + c) * K + k0 + g * 8];
      acc[nt] = MFMA16(ah, bh, acc[nt]);
      acc[nt] = MFMA16(al, bh, acc[nt]);
      acc[nt] = MFMA16(ah, bl, acc[nt]);
    }
  }
#pragma unroll
  for (int nt = 0; nt < 4; ++nt) {
    float bv = bias[n0 + nt * 16 + c];
#pragma unroll
    for (int r = 0; r < 4; ++r) acc[nt][r] += bv;
  }

  int b = (m0 >= NSEQ) ? 1 : 0;
  int nb = m0 - b * NSEQ;
  int sect = n0 >> 8;

  if (sect < 2) {
    int hloc = (n0 & 255) >> 5;
#pragma unroll
    for (int H = 0; H < 2; ++H) {
      int head = hloc + H;
#pragma unroll
      for (int r = 0; r < 4; ++r) {
        float ss = acc[2*H][r]*acc[2*H][r] + acc[2*H+1][r]*acc[2*H+1][r];
        ss += __shfl_xor(ss, 1);
        ss += __shfl_xor(ss, 2);
        ss += __shfl_xor(ss, 4);
        ss += __shfl_xor(ss, 8);
        float inv = 1.f / fmaxf(sqrtf(ss), 1e-12f);
        int n = nb + w * 16 + g * 4 + r;
        size_t orow = ((size_t)(b * NHEADS + head) * NSEQ + n) * HDIM;
#pragma unroll
        for (int half = 0; half < 2; ++half) {
          int nt = 2*H + half;
          int d = half * 16 + c;
          float val = acc[nt][r] * inv;
          if (sect == 0) {
            float scale = log1pf(expf(temp[head])) * sls[0] * LOG2E;
            val = (val + qe[head * HDIM + d]) * scale;
            ushort hh = f2bf(val);
            qhi[orow + d] = hh;
            qlo[orow + d] = f2bf(val - bf2f(hh));
          } else {
            ushort hh = f2bf(val);
            khi[orow + d] = hh;
            klo[orow + d] = f2bf(val - bf2f(hh));
          }
        }
      }
    }
  } else {
#pragma unroll
    for (int nt = 0; nt < 4; ++nt)
#pragma unroll
      for (int r = 0; r < 4; ++r)
        vbuf[w * 16 + g * 4 + r][nt * 16 + c] = acc[nt][r];
    __syncthreads();
    int hbase = (n0 - 512) >> 5;
#pragma unroll
    for (int it = 0; it < 16; ++it) {
      int dloc = (tid >> 6) * 16 + it;
      int p = tid & 63;
      int pp = p & 31;
      int nsrc = (p & 32) + (pp & 1) * 16 + (pp >> 1);
      float v = vbuf[nsrc][dloc];
      int head = hbase + (dloc >> 5), d = dloc & 31;
      vT[((size_t)((b * NHEADS + head) * HDIM + d)) * NSEQ + nb + p] = f2bf(v);
    }
  }
}

// ------- MFMA flash attention: batch-paired tiles, MFMA-L, no-max softmax -------
__launch_bounds__(256)
__global__ void attn_kernel(const ushort* __restrict__ qhi, const ushort* __restrict__ qlo,
                            const ushort* __restrict__ khi, const ushort* __restrict__ klo,
                            const ushort* __restrict__ vT, const ushort* __restrict__ tabBf,
                            const unsigned* __restrict__ idxP,
                            float* __restrict__ pO, float* __restrict__ pL) {
  __shared__ ushort tbf[10240];                        // 20 KB (table + preload slack)
  __shared__ __align__(16) ushort pbuf[8][16 * PBS];   // 9.2 KB
  int tid = threadIdx.x;
  int lane = tid & 63;
  int w = tid >> 6;
  int qb = blockIdx.x;                  // 0..35 : 64-q-row tile (both batches)
  int by = blockIdx.y;                  // 0..31
  int s = by & 3, h = by >> 2;

  // 16B-granular table preload (5 iters)
  const ushort* tsrc = tabBf + h * TABP;
#pragma unroll
  for (int i = 0; i < 5; ++i) {
    int off = i * 2048 + tid * 8;
    *(int4*)&tbf[off] = *(const int4*)&tsrc[off];
  }

  int g = lane >> 4, c = lane & 15;
  int q0 = qb * 64 + w * 16;
  size_t rb0 = (size_t)h * NSEQ;                 // b=0
  size_t rb1 = (size_t)(NHEADS + h) * NSEQ;      // b=1

  short8 qAh = *(const short8*)&qhi[(rb0 + q0 + c) * HDIM + g * 8];
  short8 qAl = *(const short8*)&qlo[(rb0 + q0 + c) * HDIM + g * 8];
  short8 qBh = *(const short8*)&qhi[(rb1 + q0 + c) * HDIM + g * 8];
  short8 qBl = *(const short8*)&qlo[(rb1 + q0 + c) * HDIM + g * 8];
  __syncthreads();

  short one = (c == 0) ? (short)0x3F80 : (short)0;   // ones-column B-frag for MFMA-L
  short8 onesB = {one, one, one, one, one, one, one, one};

  f32x4 oa0 = {0,0,0,0}, oa1 = {0,0,0,0}, ob0 = {0,0,0,0}, ob1 = {0,0,0,0};
  f32x4 la = {0,0,0,0}, lb = {0,0,0,0};
  ushort* pba = pbuf[w * 2];
  ushort* pbb = pbuf[w * 2 + 1];
  int m0 = s * MSP;

  for (int mt = m0; mt < m0 + MSP; mt += 32) {
    size_t ra0 = (rb0 + mt + c) * HDIM + g * 8;
    size_t ra1 = (rb1 + mt + c) * HDIM + g * 8;
    short8 a0h = *(const short8*)&khi[ra0];
    short8 a0l = *(const short8*)&klo[ra0];
    short8 a1h = *(const short8*)&khi[ra0 + 16 * HDIM];
    short8 a1l = *(const short8*)&klo[ra0 + 16 * HDIM];
    short8 b0h = *(const short8*)&khi[ra1];
    short8 b0l = *(const short8*)&klo[ra1];
    short8 b1h = *(const short8*)&khi[ra1 + 16 * HDIM];
    short8 b1l = *(const short8*)&klo[ra1 + 16 * HDIM];

    // shared idx pairs (batch-independent)
    size_t ib = ((size_t)(q0 + g * 4) * NCHUNK + (mt >> 5)) * 16 + c;
    unsigned i0 = idxP[ib];
    unsigned i1 = idxP[ib + (size_t)NCHUNK * 16];
    unsigned i2 = idxP[ib + (size_t)2 * NCHUNK * 16];
    unsigned i3 = idxP[ib + (size_t)3 * NCHUNK * 16];

    f32x4 sa0 = {0,0,0,0}, sa1 = {0,0,0,0}, sb0 = {0,0,0,0}, sb1 = {0,0,0,0};
    sa0 = MFMA16(qAh, a0h, sa0);
    sb0 = MFMA16(qBh, b0h, sb0);
    sa1 = MFMA16(qAh, a1h, sa1);
    sb1 = MFMA16(qBh, b1h, sb1);
    sa0 = MFMA16(qAl, a0h, sa0);
    sb0 = MFMA16(qBl, b0h, sb0);
    sa1 = MFMA16(qAl, a1h, sa1);
    sb1 = MFMA16(qBl, b1h, sb1);
    sa0 = MFMA16(qAh, a0l, sa0);
    sb0 = MFMA16(qBh, b0l, sb0);
    sa1 = MFMA16(qAh, a1l, sa1);
    sb1 = MFMA16(qBh, b1l, sb1);

    size_t va0 = ((size_t)(h * HDIM + c)) * NSEQ + mt + g * 8;
    size_t va1 = ((size_t)((NHEADS + h) * HDIM + c)) * NSEQ + mt + g * 8;
    short8 vfA0 = *(const short8*)&vT[va0];
    short8 vfA1 = *(const short8*)&vT[va0 + 16 * NSEQ];
    short8 vfB0 = *(const short8*)&vT[va1];
    short8 vfB1 = *(const short8*)&vT[va1 + 16 * NSEQ];

    unsigned ipr[4] = {i0, i1, i2, i3};
#pragma unroll
    for (int r = 0; r < 4; ++r) {
      int j0 = ipr[r] & 0xFFFF, j1 = ipr[r] >> 16;
      float bias0 = bf2f(tbf[j0]);                 // one LDS gather, shared by both batches
      float bias1 = bf2f(tbf[j1]);
      float pA0 = fexp2(sa0[r] + bias0);
      float pA1 = fexp2(sa1[r] + bias1);
      float pB0 = fexp2(sb0[r] + bias0);
      float pB1 = fexp2(sb1[r] + bias1);
      *(unsigned*)&pba[(g * 4 + r) * PBS + 2 * c] = pack_trunc(pA0, pA1);
      *(unsigned*)&pbb[(g * 4 + r) * PBS + 2 * c] = pack_trunc(pB0, pB1);
    }

    short4v paA = *(const short4v*)&pba[c * PBS + g * 8];
    short4v paB = *(const short4v*)&pba[c * PBS + g * 8 + 4];
    short8 pfa = __builtin_shufflevector(paA, paB, 0, 1, 2, 3, 4, 5, 6, 7);
    short4v pbA = *(const short4v*)&pbb[c * PBS + g * 8];
    short4v pbB = *(const short4v*)&pbb[c * PBS + g * 8 + 4];
    short8 pfb = __builtin_shufflevector(pbA, pbB, 0, 1, 2, 3, 4, 5, 6, 7);

    oa0 = MFMA16(pfa, vfA0, oa0);
    oa1 = MFMA16(pfa, vfA1, oa1);
    ob0 = MFMA16(pfb, vfB0, ob0);
    ob1 = MFMA16(pfb, vfB1, ob1);
    la  = MFMA16(pfa, onesB, la);    // L row-sums via matrix pipe
    lb  = MFMA16(pfb, onesB, lb);
  }

  size_t prow = (size_t)s * RTOT;
#pragma unroll
  for (int r = 0; r < 4; ++r) {
    size_t pra = prow + rb0 + q0 + g * 4 + r;
    pO[pra * HDIM + c]      = oa0[r];
    pO[pra * HDIM + 16 + c] = oa1[r];
    size_t prb = prow + rb1 + q0 + g * 4 + r;
    pO[prb * HDIM + c]      = ob0[r];
    pO[prb * HDIM + 16 + c] = ob1[r];
    if (c == 0) { pL[pra] = la[r]; pL[prb] = lb[r]; }
  }
}

// ------- merge splits (coalesced: lane = channel), emit split-bf16 ao -------
__global__ void merge_kernel(const float* __restrict__ pO, const float* __restrict__ pL,
                             ushort* __restrict__ aoh, ushort* __restrict__ aol) {
  int t = threadIdx.x;
  int r = blockIdx.x * 8 + (t >> 5);
  int i = t & 31;
  float L = 0.f;
#pragma unroll
  for (int sp = 0; sp < SPLITS; ++sp) L += pL[(size_t)sp * RTOT + r];
  float inv = 1.f / L;
  float acc = 0.f;
#pragma unroll
  for (int sp = 0; sp < SPLITS; ++sp) acc += pO[((size_t)sp * RTOT + r) * HDIM + i];
  float v = acc * inv;
  int n = r % NSEQ; int bh = r / NSEQ; int h = bh & (NHEADS - 1); int b = bh >> 3;
  size_t dst = (size_t)(b * NSEQ + n) * DIMC + h * HDIM + i;
  ushort hh = f2bf(v);
  aoh[dst] = hh;
  aol[dst] = f2bf(v - bf2f(hh));
}

// ------- split-bf16 MFMA GEMM (proj) -------
__launch_bounds__(256)
__global__ void gemm_mfma(const ushort* __restrict__ Ah, const ushort* __restrict__ Al,
                          const ushort* __restrict__ Bh, const ushort* __restrict__ Bl,
                          const float* __restrict__ bias, float* __restrict__ C,
                          int Nn, int K) {
  int tid = threadIdx.x;
  int lane = tid & 63;
  int w = tid >> 6;
  int g = lane >> 4, c = lane & 15;
  int n0 = blockIdx.x * 64;
  int m0 = blockIdx.y * 64 + w * 16;
  f32x4 acc[4] = {{0,0,0,0},{0,0,0,0},{0,0,0,0},{0,0,0,0}};
#pragma unroll 2
  for (int k0 = 0; k0 < K; k0 += 32) {
    short8 ah = *(const short8*)&Ah[(size_t)(m0 + c) * K + k0 + g * 8];
    short8 al = *(const short8*)&Al[(size_t)(m0 + c) * K + k0 + g * 8];
#pragma unroll
    for (int nt = 0; nt < 4; ++nt) {
      short8 bh = *(const short8*)&Bh[(size_t)(n0 + nt * 16 + c) * K + k0 + g * 8];
      short8 bl = *(const short8*)&Bl[(size_t)(n0 + nt * 16 + c) * K + k0 + g * 8];
      acc[nt] = MFMA16(ah, bh, acc[nt]);
      acc[nt] = MFMA16(al, bh, acc[nt]);
      acc[nt] = MFMA16(ah, bl, acc[nt]);
    }
  }
#pragma unroll
  for (int nt = 0; nt < 4; ++nt) {
    float bv = bias[n0 + nt * 16 + c];
#pragma unroll
    for (int r = 0; r < 4; ++r) {
      C[(size_t)(m0 + g * 4 + r) * Nn + n0 + nt * 16 + c] = acc[nt][r] + bv;
    }
  }
}

extern "C" void kernel_launch(void* const* d_in, const int* in_sizes, int n_in,
                              void* d_out, int out_size, void* d_ws, size_t ws_size,
                              hipStream_t stream) {
  const float* x    = (const float*)d_in[0];
  const int*   idx  = (const int*)d_in[1];
  const float* tbl  = (const float*)d_in[2];
  const float* sls  = (const float*)d_in[3];
  const float* Wqkv = (const float*)d_in[5];
  const float* bqkv = (const float*)d_in[6];
  const float* temp = (const float*)d_in[7];
  const float* qe   = (const float*)d_in[8];
  const float* Wp   = (const float*)d_in[9];
  const float* bp   = (const float*)d_in[10];
  const float* W1   = (const float*)d_in[11];
  const float* b1   = (const float*)d_in[12];
  const float* W2   = (const float*)d_in[13];
  const float* b2   = (const float*)d_in[14];

  float* ws   = (float*)d_ws;
  float* pO   = ws;                        // 4,718,592 f
  float* pL   = pO + 4718592;              // 147,456 f
  unsigned* idxP = (unsigned*)(pL + 147456);   // 2,654,208 u32
  ushort* u   = (ushort*)(idxP + IDXP_ELEMS);
  ushort* qhi = u;                u += (size_t)RTOT * HDIM;
  ushort* qlo = u;                u += (size_t)RTOT * HDIM;
  ushort* khi = u;                u += (size_t)RTOT * HDIM;
  ushort* klo = u;                u += (size_t)RTOT * HDIM;
  ushort* vT  = u;                u += (size_t)RTOT * HDIM;
  ushort* xh  = u;                u += NX;
  ushort* xl  = u;                u += NX;
  ushort* wqh = u;                u += NWQ;
  ushort* wql = u;                u += NWQ;
  ushort* wph = u;                u += NWP;
  ushort* wpl = u;                u += NWP;
  ushort* aoh = u;                u += (size_t)RTOT * HDIM;
  ushort* aol = u;                u += (size_t)RTOT * HDIM;
  ushort* tabBf = u;              u += 73728;   // 8*TABP=72,320 used + preload slack
  float* out  = (float*)d_out;

  setup_kernel<<<dim3(CPB_BLOCKS + SPLIT_BLOCKS + IDXP_BLOCKS), dim3(256), 0, stream>>>(
      x, Wqkv, Wp, idx, tbl, W1, b1, W2, b2,
      xh, xl, wqh, wql, wph, wpl, idxP, tabBf);
  gemm_qkv<<<dim3(12, 72), dim3(256), 0, stream>>>(
      xh, xl, wqh, wql, bqkv, temp, sls, qe, qhi, qlo, khi, klo, vT);
  attn_kernel<<<dim3(NSEQ / 64, NHEADS * SPLITS), dim3(256), 0, stream>>>(
      qhi, qlo, khi, klo, vT, tabBf, idxP, pO, pL);
  merge_kernel<<<dim3(RTOT / 8), dim3(256), 0, stream>>>(pO, pL, aoh, aol);
  gemm_mfma<<<dim3(4, 72), dim3(256), 0, stream>>>(aoh, aol, wph, wpl, bp, out, DIMC, DIMC);
}

// Round 10
// 257.263 us; speedup vs baseline: 1.0184x; 1.0184x over previous
//
#include <hip/hip_runtime.h>
#include <math.h>

#define DIMC 256
#define NHEADS 8
#define HDIM 32
#define CPBH 512
#define BB 2
#define NSEQ 2304
#define TAB 9025
#define TABP 9040                  // padded table stride
#define RTOT (BB*NHEADS*NSEQ)      // 36864
#define SPLITS 6
#define MSP (NSEQ/SPLITS)          // 384 m per split
#define PBS 36                     // pbuf row stride in u16
#define NCHUNK (NSEQ/32)           // 72
#define LOG2E 1.44269504088896340736f

#define NX  (BB*NSEQ*DIMC)         // 1,179,648
#define NWQ (3*DIMC*DIMC)          // 196,608
#define NWP (DIMC*DIMC)            // 65,536

#define SPLITX4_BLOCKS ((NX + NWQ + NWP) / 1024)       // 1408
#define IDXP_ELEMS     (NSEQ * NCHUNK * 16)            // 2,654,208
#define IDXP4_BLOCKS   (IDXP_ELEMS / 1024)             // 2592
#define CPB_BLOCKS     ((TAB + 63) / 64)               // 142

typedef unsigned short ushort;
typedef __attribute__((ext_vector_type(8))) short short8;
typedef __attribute__((ext_vector_type(4))) short short4v;
typedef __attribute__((ext_vector_type(4))) float f32x4;

#define MFMA16(a,b,c) __builtin_amdgcn_mfma_f32_16x16x32_bf16((a),(b),(c),0,0,0)

__device__ __forceinline__ ushort f2bf(float x) {          // RNE fp32->bf16
  unsigned u = __float_as_uint(x);
  u += 0x7FFFu + ((u >> 16) & 1u);
  return (ushort)(u >> 16);
}
__device__ __forceinline__ float bf2f(ushort b) {
  return __uint_as_float(((unsigned)b) << 16);
}
__device__ __forceinline__ float fexp2(float x) {
#if defined(__has_builtin)
#if __has_builtin(__builtin_amdgcn_exp2f)
  return __builtin_amdgcn_exp2f(x);
#else
  return exp2f(x);
#endif
#else
  return exp2f(x);
#endif
}
// pack trunc-bf16(p0) | trunc-bf16(p1)<<16 in one v_perm
__device__ __forceinline__ unsigned pack_trunc(float p0, float p1) {
  return __builtin_amdgcn_perm(__float_as_uint(p1), __float_as_uint(p0), 0x07060302u);
}

// ------- setup: CPB MLP (blocks FIRST) + split planes x4 + idx pair-pack x4 -------
__global__ void setup_kernel(const float* __restrict__ x, const float* __restrict__ wq,
                             const float* __restrict__ wp, const int* __restrict__ idx,
                             const float* __restrict__ tbl, const float* __restrict__ W1,
                             const float* __restrict__ b1, const float* __restrict__ W2,
                             const float* __restrict__ b2,
                             ushort* __restrict__ xh, ushort* __restrict__ xl,
                             ushort* __restrict__ wqh, ushort* __restrict__ wql,
                             ushort* __restrict__ wph, ushort* __restrict__ wpl,
                             unsigned* __restrict__ idxP, ushort* __restrict__ tabBf) {
  __shared__ float w1b[CPBH * 4];
  __shared__ float w2t[CPBH * NHEADS];
  __shared__ float part[4][64][NHEADS];
  int blk = blockIdx.x;
  int tid = threadIdx.x;
  if (blk < CPB_BLOCKS) {
    for (int i = tid; i < CPBH; i += 256) {
      w1b[i * 4 + 0] = W1[2 * i];
      w1b[i * 4 + 1] = W1[2 * i + 1];
      w1b[i * 4 + 2] = b1[i];
      w1b[i * 4 + 3] = 0.f;
    }
    for (int i = tid; i < CPBH * NHEADS; i += 256)
      w2t[(i & (CPBH - 1)) * NHEADS + (i >> 9)] = W2[i];
    int tl = tid & 63, jc = tid >> 6;
    int t = blk * 64 + tl;
    bool valid = t < TAB;
    float c0 = 0.f, c1 = 0.f;
    if (valid) { c0 = tbl[2 * t]; c1 = tbl[2 * t + 1]; }
    __syncthreads();
    float acc[NHEADS];
#pragma unroll
    for (int h = 0; h < NHEADS; ++h) acc[h] = 0.f;
    for (int j = jc * 128; j < jc * 128 + 128; ++j) {
      float4 wv = *(const float4*)&w1b[j * 4];
      float hid = fmaxf(fmaf(c0, wv.x, fmaf(c1, wv.y, wv.z)), 0.f);
      float4 wa = *(const float4*)&w2t[j * NHEADS];
      float4 wb = *(const float4*)&w2t[j * NHEADS + 4];
      acc[0] = fmaf(hid, wa.x, acc[0]);
      acc[1] = fmaf(hid, wa.y, acc[1]);
      acc[2] = fmaf(hid, wa.z, acc[2]);
      acc[3] = fmaf(hid, wa.w, acc[3]);
      acc[4] = fmaf(hid, wb.x, acc[4]);
      acc[5] = fmaf(hid, wb.y, acc[5]);
      acc[6] = fmaf(hid, wb.z, acc[6]);
      acc[7] = fmaf(hid, wb.w, acc[7]);
    }
#pragma unroll
    for (int h = 0; h < NHEADS; ++h) part[jc][tl][h] = acc[h];
    __syncthreads();
    if (jc == 0 && valid) {
#pragma unroll
      for (int h = 0; h < NHEADS; ++h) {
        float s = part[0][tl][h] + part[1][tl][h] + part[2][tl][h] + part[3][tl][h] + b2[h];
        tabBf[h * TABP + t] = f2bf(s * LOG2E);
      }
    }
  } else if (blk < CPB_BLOCKS + SPLITX4_BLOCKS) {
    int i = ((blk - CPB_BLOCKS) * 256 + tid) * 4;
    const float* src; ushort *hi, *lo; int j;
    if (i < NX)            { src = x;  hi = xh;  lo = xl;  j = i; }
    else if (i < NX + NWQ) { src = wq; hi = wqh; lo = wql; j = i - NX; }
    else                   { src = wp; hi = wph; lo = wpl; j = i - NX - NWQ; }
    float4 v = *(const float4*)&src[j];
    ushort h0 = f2bf(v.x), h1 = f2bf(v.y), h2 = f2bf(v.z), h3 = f2bf(v.w);
    uint2 hp, lp;
    hp.x = (unsigned)h0 | ((unsigned)h1 << 16);
    hp.y = (unsigned)h2 | ((unsigned)h3 << 16);
    lp.x = (unsigned)f2bf(v.x - bf2f(h0)) | ((unsigned)f2bf(v.y - bf2f(h1)) << 16);
    lp.y = (unsigned)f2bf(v.z - bf2f(h2)) | ((unsigned)f2bf(v.w - bf2f(h3)) << 16);
    *(uint2*)&hi[j] = hp;
    *(uint2*)&lo[j] = lp;
  } else {
    int t4 = (blk - CPB_BLOCKS - SPLITX4_BLOCKS) * 256 + tid;
    int cc4 = (t4 & 3) * 4;
    int ch = (t4 >> 2) % NCHUNK;
    int n = t4 / (4 * NCHUNK);
    int mbase = ch * 32 + cc4;
    int4 a = *(const int4*)&idx[(size_t)n * NSEQ + mbase];
    int4 b = *(const int4*)&idx[(size_t)n * NSEQ + mbase + 16];
    uint4 o;
    o.x = (unsigned)a.x | ((unsigned)b.x << 16);
    o.y = (unsigned)a.y | ((unsigned)b.y << 16);
    o.z = (unsigned)a.z | ((unsigned)b.z << 16);
    o.w = (unsigned)a.w | ((unsigned)b.w << 16);
    *(uint4*)&idxP[((size_t)n * NCHUNK + ch) * 16 + cc4] = o;
  }
}

// ------- fused QKV GEMM + norm/scale/split + V transpose -------
__launch_bounds__(256)
__global__ void gemm_qkv(const ushort* __restrict__ Ah, const ushort* __restrict__ Al,
                         const ushort* __restrict__ Bh, const ushort* __restrict__ Bl,
                         const float* __restrict__ bias, const float* __restrict__ temp,
                         const float* __restrict__ sls, const float* __restrict__ qe,
                         ushort* __restrict__ qhi, ushort* __restrict__ qlo,
                         ushort* __restrict__ khi, ushort* __restrict__ klo,
                         ushort* __restrict__ vT) {
  __shared__ float vbuf[64][65];
  int tid = threadIdx.x;
  int lane = tid & 63, w = tid >> 6;
  int g = lane >> 4, c = lane & 15;
  int n0 = blockIdx.x * 64, m0 = blockIdx.y * 64;
  int mw = m0 + w * 16;
  const int K = DIMC;
  f32x4 acc[4] = {{0,0,0,0},{0,0,0,0},{0,0,0,0},{0,0,0,0}};
#pragma unroll 2
  for (int k0 = 0; k0 < K; k0 += 32) {
    short8 ah = *(const short8*)&Ah[(size_t)(mw + c) * K + k0 + g * 8];
    short8 al = *(const short8*)&Al[(size_t)(mw + c) * K + k0 + g * 8];
#pragma unroll
    for (int nt = 0; nt < 4; ++nt) {
      short8 bh = *(const short8*)&Bh[(size_t)(n0 + nt * 16 + c) * K + k0 + g * 8];
      short8 bl = *(const short8*)&Bl[(size_t)(n0 + nt * 16 + c) * K + k0 + g * 8];
      acc[nt] = MFMA16(ah, bh, acc[nt]);
      acc[nt] = MFMA16(al, bh, acc[nt]);
      acc[nt] = MFMA16(ah, bl, acc[nt]);
    }
  }
#pragma unroll
  for (int nt = 0; nt < 4; ++nt) {
    float bv = bias[n0 + nt * 16 + c];
#pragma unroll
    for (int r = 0; r < 4; ++r) acc[nt][r] += bv;
  }

  int b = (m0 >= NSEQ) ? 1 : 0;
  int nb = m0 - b * NSEQ;
  int sect = n0 >> 8;

  if (sect < 2) {
    int hloc = (n0 & 255) >> 5;
#pragma unroll
    for (int H = 0; H < 2; ++H) {
      int head = hloc + H;
      float scale = log1pf(expf(temp[head])) * sls[0] * LOG2E;   // hoisted per head
#pragma unroll
      for (int r = 0; r < 4; ++r) {
        float ss = acc[2*H][r]*acc[2*H][r] + acc[2*H+1][r]*acc[2*H+1][r];
        ss += __shfl_xor(ss, 1);
        ss += __shfl_xor(ss, 2);
        ss += __shfl_xor(ss, 4);
        ss += __shfl_xor(ss, 8);
        float inv = 1.f / fmaxf(sqrtf(ss), 1e-12f);
        int n = nb + w * 16 + g * 4 + r;
        size_t orow = ((size_t)(b * NHEADS + head) * NSEQ + n) * HDIM;
#pragma unroll
        for (int half = 0; half < 2; ++half) {
          int nt = 2*H + half;
          int d = half * 16 + c;
          float val = acc[nt][r] * inv;
          if (sect == 0) {
            val = (val + qe[head * HDIM + d]) * scale;
            ushort hh = f2bf(val);
            qhi[orow + d] = hh;
            qlo[orow + d] = f2bf(val - bf2f(hh));
          } else {
            ushort hh = f2bf(val);
            khi[orow + d] = hh;
            klo[orow + d] = f2bf(val - bf2f(hh));
          }
        }
      }
    }
  } else {
#pragma unroll
    for (int nt = 0; nt < 4; ++nt)
#pragma unroll
      for (int r = 0; r < 4; ++r)
        vbuf[w * 16 + g * 4 + r][nt * 16 + c] = acc[nt][r];
    __syncthreads();
    int hbase = (n0 - 512) >> 5;
#pragma unroll
    for (int it = 0; it < 16; ++it) {
      int dloc = (tid >> 6) * 16 + it;
      int p = tid & 63;
      int pp = p & 31;
      int nsrc = (p & 32) + (pp & 1) * 16 + (pp >> 1);
      float v = vbuf[nsrc][dloc];
      int head = hbase + (dloc >> 5), d = dloc & 31;
      vT[((size_t)((b * NHEADS + head) * HDIM + d)) * NSEQ + nb + p] = f2bf(v);
    }
  }
}

// ------- MFMA flash attention: batch-paired + software-pipelined + MFMA-L -------
__launch_bounds__(256)
__global__ void attn_kernel(const ushort* __restrict__ qhi, const ushort* __restrict__ qlo,
                            const ushort* __restrict__ khi, const ushort* __restrict__ klo,
                            const ushort* __restrict__ vT, const ushort* __restrict__ tabBf,
                            const unsigned* __restrict__ idxP,
                            float* __restrict__ pO, float* __restrict__ pL) {
  __shared__ ushort tbf[10240];                        // 20 KB
  __shared__ __align__(16) ushort pbuf[8][16 * PBS];   // 9.2 KB
  int tid = threadIdx.x;
  int lane = tid & 63;
  int w = tid >> 6;
  int qb = blockIdx.x;                  // 0..35 : 64-q-row tile (both batches)
  int s = blockIdx.y;                   // 0..5
  int h = blockIdx.z;                   // 0..7

  const ushort* tsrc = tabBf + h * TABP;
#pragma unroll
  for (int i = 0; i < 5; ++i) {
    int off = i * 2048 + tid * 8;
    *(int4*)&tbf[off] = *(const int4*)&tsrc[off];
  }

  int g = lane >> 4, c = lane & 15;
  int q0 = qb * 64 + w * 16;
  size_t rb0 = (size_t)h * NSEQ;                 // b=0
  size_t rb1 = (size_t)(NHEADS + h) * NSEQ;      // b=1

  short8 qAh = *(const short8*)&qhi[(rb0 + q0 + c) * HDIM + g * 8];
  short8 qAl = *(const short8*)&qlo[(rb0 + q0 + c) * HDIM + g * 8];
  short8 qBh = *(const short8*)&qhi[(rb1 + q0 + c) * HDIM + g * 8];
  short8 qBl = *(const short8*)&qlo[(rb1 + q0 + c) * HDIM + g * 8];
  __syncthreads();

  short one = (c == 0) ? (short)0x3F80 : (short)0;
  short8 onesB = {one, one, one, one, one, one, one, one};

  f32x4 oa0 = {0,0,0,0}, oa1 = {0,0,0,0}, ob0 = {0,0,0,0}, ob1 = {0,0,0,0};
  f32x4 la = {0,0,0,0}, lb = {0,0,0,0};
  ushort* pba = pbuf[w * 2];
  ushort* pbb = pbuf[w * 2 + 1];
  int m0 = s * MSP;

#define LOADKB(MT, A0H, A0L, A1H, A1L, B0H, B0L, B1H, B1L, I0, I1, I2, I3) do { \
    size_t ra0_ = (rb0 + (MT) + c) * HDIM + g * 8;                    \
    size_t ra1_ = (rb1 + (MT) + c) * HDIM + g * 8;                    \
    A0H = *(const short8*)&khi[ra0_];                                 \
    A0L = *(const short8*)&klo[ra0_];                                 \
    A1H = *(const short8*)&khi[ra0_ + 16 * HDIM];                     \
    A1L = *(const short8*)&klo[ra0_ + 16 * HDIM];                     \
    B0H = *(const short8*)&khi[ra1_];                                 \
    B0L = *(const short8*)&klo[ra1_];                                 \
    B1H = *(const short8*)&khi[ra1_ + 16 * HDIM];                     \
    B1L = *(const short8*)&klo[ra1_ + 16 * HDIM];                     \
    size_t ib_ = ((size_t)(q0 + g * 4) * NCHUNK + ((MT) >> 5)) * 16 + c; \
    I0 = idxP[ib_];                                                   \
    I1 = idxP[ib_ + (size_t)NCHUNK * 16];                             \
    I2 = idxP[ib_ + (size_t)2 * NCHUNK * 16];                         \
    I3 = idxP[ib_ + (size_t)3 * NCHUNK * 16];                         \
  } while (0)

  short8 a0h, a0l, a1h, a1l, b0h, b0l, b1h, b1l;
  unsigned i0, i1, i2, i3;
  LOADKB(m0, a0h, a0l, a1h, a1l, b0h, b0l, b1h, b1l, i0, i1, i2, i3);

  for (int mt = m0; mt < m0 + MSP; mt += 32) {
    int mtn = (mt + 32 < m0 + MSP) ? (mt + 32) : m0;
    short8 n0h, n0l, n1h, n1l, p0h, p0l, p1h, p1l;
    unsigned j0, j1, j2, j3;
    LOADKB(mtn, n0h, n0l, n1h, n1l, p0h, p0l, p1h, p1l, j0, j1, j2, j3);  // prefetch

    f32x4 sa0 = {0,0,0,0}, sa1 = {0,0,0,0}, sb0 = {0,0,0,0}, sb1 = {0,0,0,0};
    sa0 = MFMA16(qAh, a0h, sa0);
    sb0 = MFMA16(qBh, b0h, sb0);
    sa1 = MFMA16(qAh, a1h, sa1);
    sb1 = MFMA16(qBh, b1h, sb1);
    sa0 = MFMA16(qAl, a0h, sa0);
    sb0 = MFMA16(qBl, b0h, sb0);
    sa1 = MFMA16(qAl, a1h, sa1);
    sb1 = MFMA16(qBl, b1h, sb1);
    sa0 = MFMA16(qAh, a0l, sa0);
    sb0 = MFMA16(qBh, b0l, sb0);
    sa1 = MFMA16(qAh, a1l, sa1);
    sb1 = MFMA16(qBh, b1l, sb1);

    size_t va0 = ((size_t)(h * HDIM + c)) * NSEQ + mt + g * 8;
    size_t va1 = ((size_t)((NHEADS + h) * HDIM + c)) * NSEQ + mt + g * 8;
    short8 vfA0 = *(const short8*)&vT[va0];
    short8 vfA1 = *(const short8*)&vT[va0 + 16 * NSEQ];
    short8 vfB0 = *(const short8*)&vT[va1];
    short8 vfB1 = *(const short8*)&vT[va1 + 16 * NSEQ];

    unsigned ipr[4] = {i0, i1, i2, i3};
#pragma unroll
    for (int r = 0; r < 4; ++r) {
      int k0 = ipr[r] & 0xFFFF, k1 = ipr[r] >> 16;
      float bias0 = bf2f(tbf[k0]);                 // one LDS gather, both batches
      float bias1 = bf2f(tbf[k1]);
      float pA0 = fexp2(sa0[r] + bias0);
      float pA1 = fexp2(sa1[r] + bias1);
      float pB0 = fexp2(sb0[r] + bias0);
      float pB1 = fexp2(sb1[r] + bias1);
      *(unsigned*)&pba[(g * 4 + r) * PBS + 2 * c] = pack_trunc(pA0, pA1);
      *(unsigned*)&pbb[(g * 4 + r) * PBS + 2 * c] = pack_trunc(pB0, pB1);
    }

    short4v paA = *(const short4v*)&pba[c * PBS + g * 8];
    short4v paB = *(const short4v*)&pba[c * PBS + g * 8 + 4];
    short8 pfa = __builtin_shufflevector(paA, paB, 0, 1, 2, 3, 4, 5, 6, 7);
    short4v pbA = *(const short4v*)&pbb[c * PBS + g * 8];
    short4v pbB = *(const short4v*)&pbb[c * PBS + g * 8 + 4];
    short8 pfb = __builtin_shufflevector(pbA, pbB, 0, 1, 2, 3, 4, 5, 6, 7);

    oa0 = MFMA16(pfa, vfA0, oa0);
    oa1 = MFMA16(pfa, vfA1, oa1);
    ob0 = MFMA16(pfb, vfB0, ob0);
    ob1 = MFMA16(pfb, vfB1, ob1);
    la  = MFMA16(pfa, onesB, la);
    lb  = MFMA16(pfb, onesB, lb);

    a0h = n0h; a0l = n0l; a1h = n1h; a1l = n1l;
    b0h = p0h; b0l = p0l; b1h = p1h; b1l = p1l;
    i0 = j0; i1 = j1; i2 = j2; i3 = j3;
  }
#undef LOADKB

  size_t prow = (size_t)s * RTOT;
#pragma unroll
  for (int r = 0; r < 4; ++r) {
    size_t pra = prow + rb0 + q0 + g * 4 + r;
    pO[pra * HDIM + c]      = oa0[r];
    pO[pra * HDIM + 16 + c] = oa1[r];
    size_t prb = prow + rb1 + q0 + g * 4 + r;
    pO[prb * HDIM + c]      = ob0[r];
    pO[prb * HDIM + 16 + c] = ob1[r];
    if (c == 0) { pL[pra] = la[r]; pL[prb] = lb[r]; }
  }
}

// ------- merge splits (coalesced: lane = channel), emit split-bf16 ao -------
__global__ void merge_kernel(const float* __restrict__ pO, const float* __restrict__ pL,
                             ushort* __restrict__ aoh, ushort* __restrict__ aol) {
  int t = threadIdx.x;
  int r = blockIdx.x * 8 + (t >> 5);
  int i = t & 31;
  float L = 0.f;
#pragma unroll
  for (int sp = 0; sp < SPLITS; ++sp) L += pL[(size_t)sp * RTOT + r];
  float inv = 1.f / L;
  float acc = 0.f;
#pragma unroll
  for (int sp = 0; sp < SPLITS; ++sp) acc += pO[((size_t)sp * RTOT + r) * HDIM + i];
  float v = acc * inv;
  int n = r % NSEQ; int bh = r / NSEQ; int h = bh & (NHEADS - 1); int b = bh >> 3;
  size_t dst = (size_t)(b * NSEQ + n) * DIMC + h * HDIM + i;
  ushort hh = f2bf(v);
  aoh[dst] = hh;
  aol[dst] = f2bf(v - bf2f(hh));
}

// ------- split-bf16 MFMA GEMM (proj) -------
__launch_bounds__(256)
__global__ void gemm_mfma(const ushort* __restrict__ Ah, const ushort* __restrict__ Al,
                          const ushort* __restrict__ Bh, const ushort* __restrict__ Bl,
                          const float* __restrict__ bias, float* __restrict__ C,
                          int Nn, int K) {
  int tid = threadIdx.x;
  int lane = tid & 63;
  int w = tid >> 6;
  int g = lane >> 4, c = lane & 15;
  int n0 = blockIdx.x * 64;
  int m0 = blockIdx.y * 64 + w * 16;
  f32x4 acc[4] = {{0,0,0,0},{0,0,0,0},{0,0,0,0},{0,0,0,0}};
#pragma unroll 2
  for (int k0 = 0; k0 < K; k0 += 32) {
    short8 ah = *(const short8*)&Ah[(size_t)(m0 + c) * K + k0 + g * 8];
    short8 al = *(const short8*)&Al[(size_t)(m0 + c) * K + k0 + g * 8];
#pragma unroll
    for (int nt = 0; nt < 4; ++nt) {
      short8 bh = *(const short8*)&Bh[(size_t)(n0 + nt * 16 + c) * K + k0 + g * 8];
      short8 bl = *(const short8*)&Bl[(size_t)(n0 + nt * 16 + c) * K + k0 + g * 8];
      acc[nt] = MFMA16(ah, bh, acc[nt]);
      acc[nt] = MFMA16(al, bh, acc[nt]);
      acc[nt] = MFMA16(ah, bl, acc[nt]);
    }
  }
#pragma unroll
  for (int nt = 0; nt < 4; ++nt) {
    float bv = bias[n0 + nt * 16 + c];
#pragma unroll
    for (int r = 0; r < 4; ++r) {
      C[(size_t)(m0 + g * 4 + r) * Nn + n0 + nt * 16 + c] = acc[nt][r] + bv;
    }
  }
}

extern "C" void kernel_launch(void* const* d_in, const int* in_sizes, int n_in,
                              void* d_out, int out_size, void* d_ws, size_t ws_size,
                              hipStream_t stream) {
  const float* x    = (const float*)d_in[0];
  const int*   idx  = (const int*)d_in[1];
  const float* tbl  = (const float*)d_in[2];
  const float* sls  = (const float*)d_in[3];
  const float* Wqkv = (const float*)d_in[5];
  const float* bqkv = (const float*)d_in[6];
  const float* temp = (const float*)d_in[7];
  const float* qe   = (const float*)d_in[8];
  const float* Wp   = (const float*)d_in[9];
  const float* bp   = (const float*)d_in[10];
  const float* W1   = (const float*)d_in[11];
  const float* b1   = (const float*)d_in[12];
  const float* W2   = (const float*)d_in[13];
  const float* b2   = (const float*)d_in[14];

  float* ws   = (float*)d_ws;
  float* pO   = ws;                            // SPLITS*RTOT*HDIM = 7,077,888 f
  float* pL   = pO + (size_t)SPLITS * RTOT * HDIM;   // 221,184 f
  unsigned* idxP = (unsigned*)(pL + (size_t)SPLITS * RTOT);
  ushort* u   = (ushort*)(idxP + IDXP_ELEMS);
  ushort* qhi = u;                u += (size_t)RTOT * HDIM;
  ushort* qlo = u;                u += (size_t)RTOT * HDIM;
  ushort* khi = u;                u += (size_t)RTOT * HDIM;
  ushort* klo = u;                u += (size_t)RTOT * HDIM;
  ushort* vT  = u;                u += (size_t)RTOT * HDIM;
  ushort* xh  = u;                u += NX;
  ushort* xl  = u;                u += NX;
  ushort* wqh = u;                u += NWQ;
  ushort* wql = u;                u += NWQ;
  ushort* wph = u;                u += NWP;
  ushort* wpl = u;                u += NWP;
  ushort* aoh = u;                u += (size_t)RTOT * HDIM;
  ushort* aol = u;                u += (size_t)RTOT * HDIM;
  ushort* tabBf = u;              u += 73728;   // 8*TABP = 72,320 + slack
  float* out  = (float*)d_out;

  setup_kernel<<<dim3(CPB_BLOCKS + SPLITX4_BLOCKS + IDXP4_BLOCKS), dim3(256), 0, stream>>>(
      x, Wqkv, Wp, idx, tbl, W1, b1, W2, b2,
      xh, xl, wqh, wql, wph, wpl, idxP, tabBf);
  gemm_qkv<<<dim3(12, 72), dim3(256), 0, stream>>>(
      xh, xl, wqh, wql, bqkv, temp, sls, qe, qhi, qlo, khi, klo, vT);
  attn_kernel<<<dim3(NSEQ / 64, SPLITS, NHEADS), dim3(256), 0, stream>>>(
      qhi, qlo, khi, klo, vT, tabBf, idxP, pO, pL);
  merge_kernel<<<dim3(RTOT / 8), dim3(256), 0, stream>>>(pO, pL, aoh, aol);
  gemm_mfma<<<dim3(4, 72), dim3(256), 0, stream>>>(aoh, aol, wph, wpl, bp, out, DIMC, DIMC);
}

// Round 11
// 216.690 us; speedup vs baseline: 1.2091x; 1.1872x over previous
//
#include <hip/hip_runtime.h>
#include <math.h>

#define DIMC 256
#define NHEADS 8
#define HDIM 32
#define CPBH 512
#define BB 2
#define NSEQ 2304
#define TAB 9025
#define TABP 9040                  // padded table stride
#define RTOT (BB*NHEADS*NSEQ)      // 36864
#define SPLITS 4
#define MSP (NSEQ/SPLITS)          // 576 m per split
#define PBS 36                     // pbuf row stride in u16
#define NCHUNK (NSEQ/32)           // 72
#define LOG2E 1.44269504088896340736f

#define NX  (BB*NSEQ*DIMC)         // 1,179,648
#define NWQ (3*DIMC*DIMC)          // 196,608
#define NWP (DIMC*DIMC)            // 65,536

#define SPLITX4_BLOCKS ((NX + NWQ + NWP) / 1024)       // 1408
#define IDXP_ELEMS     (NSEQ * NCHUNK * 16)            // 2,654,208
#define IDXP4_BLOCKS   (IDXP_ELEMS / 1024)             // 2592
#define CPB_BLOCKS     ((TAB + 63) / 64)               // 142

typedef unsigned short ushort;
typedef __attribute__((ext_vector_type(8))) short short8;
typedef __attribute__((ext_vector_type(4))) short short4v;
typedef __attribute__((ext_vector_type(4))) float f32x4;

#define MFMA16(a,b,c) __builtin_amdgcn_mfma_f32_16x16x32_bf16((a),(b),(c),0,0,0)

__device__ __forceinline__ ushort f2bf(float x) {          // RNE fp32->bf16
  unsigned u = __float_as_uint(x);
  u += 0x7FFFu + ((u >> 16) & 1u);
  return (ushort)(u >> 16);
}
__device__ __forceinline__ float bf2f(ushort b) {
  return __uint_as_float(((unsigned)b) << 16);
}
__device__ __forceinline__ float fexp2(float x) {
#if defined(__has_builtin)
#if __has_builtin(__builtin_amdgcn_exp2f)
  return __builtin_amdgcn_exp2f(x);
#else
  return exp2f(x);
#endif
#else
  return exp2f(x);
#endif
}
// pack trunc-bf16(p0) | trunc-bf16(p1)<<16 in one v_perm
__device__ __forceinline__ unsigned pack_trunc(float p0, float p1) {
  return __builtin_amdgcn_perm(__float_as_uint(p1), __float_as_uint(p0), 0x07060302u);
}

// ------- setup: CPB MLP (blocks FIRST) + split planes x4 + idx pair-pack x4 -------
__global__ void setup_kernel(const float* __restrict__ x, const float* __restrict__ wq,
                             const float* __restrict__ wp, const int* __restrict__ idx,
                             const float* __restrict__ tbl, const float* __restrict__ W1,
                             const float* __restrict__ b1, const float* __restrict__ W2,
                             const float* __restrict__ b2,
                             ushort* __restrict__ xh, ushort* __restrict__ xl,
                             ushort* __restrict__ wqh, ushort* __restrict__ wql,
                             ushort* __restrict__ wph, ushort* __restrict__ wpl,
                             unsigned* __restrict__ idxP, ushort* __restrict__ tabBf) {
  __shared__ float w1b[CPBH * 4];
  __shared__ float w2t[CPBH * NHEADS];
  __shared__ float part[4][64][NHEADS];
  int blk = blockIdx.x;
  int tid = threadIdx.x;
  if (blk < CPB_BLOCKS) {
    for (int i = tid; i < CPBH; i += 256) {
      w1b[i * 4 + 0] = W1[2 * i];
      w1b[i * 4 + 1] = W1[2 * i + 1];
      w1b[i * 4 + 2] = b1[i];
      w1b[i * 4 + 3] = 0.f;
    }
    for (int i = tid; i < CPBH * NHEADS; i += 256)
      w2t[(i & (CPBH - 1)) * NHEADS + (i >> 9)] = W2[i];
    int tl = tid & 63, jc = tid >> 6;
    int t = blk * 64 + tl;
    bool valid = t < TAB;
    float c0 = 0.f, c1 = 0.f;
    if (valid) { c0 = tbl[2 * t]; c1 = tbl[2 * t + 1]; }
    __syncthreads();
    float acc[NHEADS];
#pragma unroll
    for (int h = 0; h < NHEADS; ++h) acc[h] = 0.f;
    for (int j = jc * 128; j < jc * 128 + 128; ++j) {
      float4 wv = *(const float4*)&w1b[j * 4];
      float hid = fmaxf(fmaf(c0, wv.x, fmaf(c1, wv.y, wv.z)), 0.f);
      float4 wa = *(const float4*)&w2t[j * NHEADS];
      float4 wb = *(const float4*)&w2t[j * NHEADS + 4];
      acc[0] = fmaf(hid, wa.x, acc[0]);
      acc[1] = fmaf(hid, wa.y, acc[1]);
      acc[2] = fmaf(hid, wa.z, acc[2]);
      acc[3] = fmaf(hid, wa.w, acc[3]);
      acc[4] = fmaf(hid, wb.x, acc[4]);
      acc[5] = fmaf(hid, wb.y, acc[5]);
      acc[6] = fmaf(hid, wb.z, acc[6]);
      acc[7] = fmaf(hid, wb.w, acc[7]);
    }
#pragma unroll
    for (int h = 0; h < NHEADS; ++h) part[jc][tl][h] = acc[h];
    __syncthreads();
    if (jc == 0 && valid) {
#pragma unroll
      for (int h = 0; h < NHEADS; ++h) {
        float s = part[0][tl][h] + part[1][tl][h] + part[2][tl][h] + part[3][tl][h] + b2[h];
        tabBf[h * TABP + t] = f2bf(s * LOG2E);
      }
    }
  } else if (blk < CPB_BLOCKS + SPLITX4_BLOCKS) {
    int i = ((blk - CPB_BLOCKS) * 256 + tid) * 4;
    const float* src; ushort *hi, *lo; int j;
    if (i < NX)            { src = x;  hi = xh;  lo = xl;  j = i; }
    else if (i < NX + NWQ) { src = wq; hi = wqh; lo = wql; j = i - NX; }
    else                   { src = wp; hi = wph; lo = wpl; j = i - NX - NWQ; }
    float4 v = *(const float4*)&src[j];
    ushort h0 = f2bf(v.x), h1 = f2bf(v.y), h2 = f2bf(v.z), h3 = f2bf(v.w);
    uint2 hp, lp;
    hp.x = (unsigned)h0 | ((unsigned)h1 << 16);
    hp.y = (unsigned)h2 | ((unsigned)h3 << 16);
    lp.x = (unsigned)f2bf(v.x - bf2f(h0)) | ((unsigned)f2bf(v.y - bf2f(h1)) << 16);
    lp.y = (unsigned)f2bf(v.z - bf2f(h2)) | ((unsigned)f2bf(v.w - bf2f(h3)) << 16);
    *(uint2*)&hi[j] = hp;
    *(uint2*)&lo[j] = lp;
  } else {
    int t4 = (blk - CPB_BLOCKS - SPLITX4_BLOCKS) * 256 + tid;
    int cc4 = (t4 & 3) * 4;
    int ch = (t4 >> 2) % NCHUNK;
    int n = t4 / (4 * NCHUNK);
    int mbase = ch * 32 + cc4;
    int4 a = *(const int4*)&idx[(size_t)n * NSEQ + mbase];
    int4 b = *(const int4*)&idx[(size_t)n * NSEQ + mbase + 16];
    uint4 o;
    o.x = (unsigned)a.x | ((unsigned)b.x << 16);
    o.y = (unsigned)a.y | ((unsigned)b.y << 16);
    o.z = (unsigned)a.z | ((unsigned)b.z << 16);
    o.w = (unsigned)a.w | ((unsigned)b.w << 16);
    *(uint4*)&idxP[((size_t)n * NCHUNK + ch) * 16 + cc4] = o;
  }
}

// ------- fused QKV GEMM + norm/scale/split + V transpose -------
__launch_bounds__(256)
__global__ void gemm_qkv(const ushort* __restrict__ Ah, const ushort* __restrict__ Al,
                         const ushort* __restrict__ Bh, const ushort* __restrict__ Bl,
                         const float* __restrict__ bias, const float* __restrict__ temp,
                         const float* __restrict__ sls, const float* __restrict__ qe,
                         ushort* __restrict__ qhi, ushort* __restrict__ qlo,
                         ushort* __restrict__ khi, ushort* __restrict__ klo,
                         ushort* __restrict__ vT) {
  __shared__ float vbuf[64][65];
  int tid = threadIdx.x;
  int lane = tid & 63, w = tid >> 6;
  int g = lane >> 4, c = lane & 15;
  int n0 = blockIdx.x * 64, m0 = blockIdx.y * 64;
  int mw = m0 + w * 16;
  const int K = DIMC;
  f32x4 acc[4] = {{0,0,0,0},{0,0,0,0},{0,0,0,0},{0,0,0,0}};
#pragma unroll 2
  for (int k0 = 0; k0 < K; k0 += 32) {
    short8 ah = *(const short8*)&Ah[(size_t)(mw + c) * K + k0 + g * 8];
    short8 al = *(const short8*)&Al[(size_t)(mw + c) * K + k0 + g * 8];
#pragma unroll
    for (int nt = 0; nt < 4; ++nt) {
      short8 bh = *(const short8*)&Bh[(size_t)(n0 + nt * 16 + c) * K + k0 + g * 8];
      short8 bl = *(const short8*)&Bl[(size_t)(n0 + nt * 16 + c) * K + k0 + g * 8];
      acc[nt] = MFMA16(ah, bh, acc[nt]);
      acc[nt] = MFMA16(al, bh, acc[nt]);
      acc[nt] = MFMA16(ah, bl, acc[nt]);
    }
  }
#pragma unroll
  for (int nt = 0; nt < 4; ++nt) {
    float bv = bias[n0 + nt * 16 + c];
#pragma unroll
    for (int r = 0; r < 4; ++r) acc[nt][r] += bv;
  }

  int b = (m0 >= NSEQ) ? 1 : 0;
  int nb = m0 - b * NSEQ;
  int sect = n0 >> 8;

  if (sect < 2) {
    int hloc = (n0 & 255) >> 5;
#pragma unroll
    for (int H = 0; H < 2; ++H) {
      int head = hloc + H;
      float scale = log1pf(expf(temp[head])) * sls[0] * LOG2E;
#pragma unroll
      for (int r = 0; r < 4; ++r) {
        float ss = acc[2*H][r]*acc[2*H][r] + acc[2*H+1][r]*acc[2*H+1][r];
        ss += __shfl_xor(ss, 1);
        ss += __shfl_xor(ss, 2);
        ss += __shfl_xor(ss, 4);
        ss += __shfl_xor(ss, 8);
        float inv = 1.f / fmaxf(sqrtf(ss), 1e-12f);
        int n = nb + w * 16 + g * 4 + r;
        size_t orow = ((size_t)(b * NHEADS + head) * NSEQ + n) * HDIM;
#pragma unroll
        for (int half = 0; half < 2; ++half) {
          int nt = 2*H + half;
          int d = half * 16 + c;
          float val = acc[nt][r] * inv;
          if (sect == 0) {
            val = (val + qe[head * HDIM + d]) * scale;
            ushort hh = f2bf(val);
            qhi[orow + d] = hh;
            qlo[orow + d] = f2bf(val - bf2f(hh));
          } else {
            ushort hh = f2bf(val);
            khi[orow + d] = hh;
            klo[orow + d] = f2bf(val - bf2f(hh));
          }
        }
      }
    }
  } else {
#pragma unroll
    for (int nt = 0; nt < 4; ++nt)
#pragma unroll
      for (int r = 0; r < 4; ++r)
        vbuf[w * 16 + g * 4 + r][nt * 16 + c] = acc[nt][r];
    __syncthreads();
    int hbase = (n0 - 512) >> 5;
#pragma unroll
    for (int it = 0; it < 16; ++it) {
      int dloc = (tid >> 6) * 16 + it;
      int p = tid & 63;
      int pp = p & 31;
      int nsrc = (p & 32) + (pp & 1) * 16 + (pp >> 1);
      float v = vbuf[nsrc][dloc];
      int head = hbase + (dloc >> 5), d = dloc & 31;
      vT[((size_t)((b * NHEADS + head) * HDIM + d)) * NSEQ + nb + p] = f2bf(v);
    }
  }
}

// ------- MFMA flash attention: r8 structure (2 q-tiles share K/vT) + MFMA-L -------
__launch_bounds__(256)
__global__ void attn_kernel(const ushort* __restrict__ qhi, const ushort* __restrict__ qlo,
                            const ushort* __restrict__ khi, const ushort* __restrict__ klo,
                            const ushort* __restrict__ vT, const ushort* __restrict__ tabBf,
                            const unsigned* __restrict__ idxP,
                            float* __restrict__ pO, float* __restrict__ pL) {
  __shared__ ushort tbf[10240];                        // 20 KB
  __shared__ __align__(16) ushort pbuf[8][16 * PBS];   // 9.2 KB
  int tid = threadIdx.x;
  int lane = tid & 63;
  int w = tid >> 6;
  int qb = blockIdx.x;                  // 0..17 : 128-q-row tile
  int by = blockIdx.y;                  // 0..63
  int s = by & 3, bh = by >> 2;
  int h = bh & (NHEADS - 1);

  const ushort* tsrc = tabBf + h * TABP;
#pragma unroll
  for (int i = 0; i < 5; ++i) {
    int off = i * 2048 + tid * 8;
    *(int4*)&tbf[off] = *(const int4*)&tsrc[off];
  }

  int g = lane >> 4, c = lane & 15;
  int q0 = qb * 128 + w * 16;           // tile A rows
  int q1 = q0 + 64;                     // tile B rows
  size_t rowbase = (size_t)bh * NSEQ;

  short8 qAh = *(const short8*)&qhi[(rowbase + q0 + c) * HDIM + g * 8];
  short8 qAl = *(const short8*)&qlo[(rowbase + q0 + c) * HDIM + g * 8];
  short8 qBh = *(const short8*)&qhi[(rowbase + q1 + c) * HDIM + g * 8];
  short8 qBl = *(const short8*)&qlo[(rowbase + q1 + c) * HDIM + g * 8];
  __syncthreads();

  short one = (c == 0) ? (short)0x3F80 : (short)0;   // ones-column B-frag for MFMA-L
  short8 onesB = {one, one, one, one, one, one, one, one};

  f32x4 oa0 = {0,0,0,0}, oa1 = {0,0,0,0}, ob0 = {0,0,0,0}, ob1 = {0,0,0,0};
  f32x4 la = {0,0,0,0}, lb = {0,0,0,0};
  ushort* pba = pbuf[w * 2];
  ushort* pbb = pbuf[w * 2 + 1];
  int m0 = s * MSP;

#define LOADK(MT, D0H, D0L, D1H, D1L, IA0, IA1, IA2, IA3, IB0, IB1, IB2, IB3) do { \
    size_t ra_ = (rowbase + (MT) + c) * HDIM + g * 8;                 \
    D0H = *(const short8*)&khi[ra_];                                  \
    D0L = *(const short8*)&klo[ra_];                                  \
    D1H = *(const short8*)&khi[ra_ + 16 * HDIM];                      \
    D1L = *(const short8*)&klo[ra_ + 16 * HDIM];                      \
    size_t ia_ = ((size_t)(q0 + g * 4) * NCHUNK + ((MT) >> 5)) * 16 + c; \
    IA0 = idxP[ia_];                                                  \
    IA1 = idxP[ia_ + (size_t)NCHUNK * 16];                            \
    IA2 = idxP[ia_ + (size_t)2 * NCHUNK * 16];                        \
    IA3 = idxP[ia_ + (size_t)3 * NCHUNK * 16];                        \
    size_t ibx_ = ((size_t)(q1 + g * 4) * NCHUNK + ((MT) >> 5)) * 16 + c; \
    IB0 = idxP[ibx_];                                                 \
    IB1 = idxP[ibx_ + (size_t)NCHUNK * 16];                           \
    IB2 = idxP[ibx_ + (size_t)2 * NCHUNK * 16];                       \
    IB3 = idxP[ibx_ + (size_t)3 * NCHUNK * 16];                       \
  } while (0)

  short8 c0h, c0l, c1h, c1l;
  unsigned ia0, ia1, ia2, ia3, ib0, ib1, ib2, ib3;
  LOADK(m0, c0h, c0l, c1h, c1l, ia0, ia1, ia2, ia3, ib0, ib1, ib2, ib3);

  for (int mt = m0; mt < m0 + MSP; mt += 32) {
    int mtn = (mt + 32 < m0 + MSP) ? (mt + 32) : m0;
    short8 n0h, n0l, n1h, n1l;
    unsigned ja0, ja1, ja2, ja3, jb0, jb1, jb2, jb3;
    LOADK(mtn, n0h, n0l, n1h, n1l, ja0, ja1, ja2, ja3, jb0, jb1, jb2, jb3);

    // QK^T both q-tiles, K-frags shared
    f32x4 sa0 = {0,0,0,0}, sa1 = {0,0,0,0}, sb0 = {0,0,0,0}, sb1 = {0,0,0,0};
    sa0 = MFMA16(qAh, c0h, sa0);
    sb0 = MFMA16(qBh, c0h, sb0);
    sa1 = MFMA16(qAh, c1h, sa1);
    sb1 = MFMA16(qBh, c1h, sb1);
    sa0 = MFMA16(qAl, c0h, sa0);
    sb0 = MFMA16(qBl, c0h, sb0);
    sa1 = MFMA16(qAl, c1h, sa1);
    sb1 = MFMA16(qBl, c1h, sb1);
    sa0 = MFMA16(qAh, c0l, sa0);
    sb0 = MFMA16(qBh, c0l, sb0);
    sa1 = MFMA16(qAh, c1l, sa1);
    sb1 = MFMA16(qBh, c1l, sb1);

    size_t va = ((size_t)(bh * HDIM + c)) * NSEQ + mt + g * 8;   // vT shared
    short8 vf0 = *(const short8*)&vT[va];
    short8 vf1 = *(const short8*)&vT[va + 16 * NSEQ];

    unsigned ipa[4] = {ia0, ia1, ia2, ia3};
    unsigned ipb[4] = {ib0, ib1, ib2, ib3};
#pragma unroll
    for (int r = 0; r < 4; ++r) {
      int k0 = ipa[r] & 0xFFFF, k1 = ipa[r] >> 16;
      float pA0 = fexp2(sa0[r] + bf2f(tbf[k0]));
      float pA1 = fexp2(sa1[r] + bf2f(tbf[k1]));
      *(unsigned*)&pba[(g * 4 + r) * PBS + 2 * c] = pack_trunc(pA0, pA1);
    }
#pragma unroll
    for (int r = 0; r < 4; ++r) {
      int k0 = ipb[r] & 0xFFFF, k1 = ipb[r] >> 16;
      float pB0 = fexp2(sb0[r] + bf2f(tbf[k0]));
      float pB1 = fexp2(sb1[r] + bf2f(tbf[k1]));
      *(unsigned*)&pbb[(g * 4 + r) * PBS + 2 * c] = pack_trunc(pB0, pB1);
    }

    short4v paA = *(const short4v*)&pba[c * PBS + g * 8];
    short4v paB = *(const short4v*)&pba[c * PBS + g * 8 + 4];
    short8 pfa = __builtin_shufflevector(paA, paB, 0, 1, 2, 3, 4, 5, 6, 7);
    short4v pbA = *(const short4v*)&pbb[c * PBS + g * 8];
    short4v pbB = *(const short4v*)&pbb[c * PBS + g * 8 + 4];
    short8 pfb = __builtin_shufflevector(pbA, pbB, 0, 1, 2, 3, 4, 5, 6, 7);

    oa0 = MFMA16(pfa, vf0, oa0);
    oa1 = MFMA16(pfa, vf1, oa1);
    ob0 = MFMA16(pfb, vf0, ob0);
    ob1 = MFMA16(pfb, vf1, ob1);
    la  = MFMA16(pfa, onesB, la);    // L row-sums via matrix pipe (consistent with P)
    lb  = MFMA16(pfb, onesB, lb);

    c0h = n0h; c0l = n0l; c1h = n1h; c1l = n1l;
    ia0 = ja0; ia1 = ja1; ia2 = ja2; ia3 = ja3;
    ib0 = jb0; ib1 = jb1; ib2 = jb2; ib3 = jb3;
  }
#undef LOADK

  size_t prow0 = (size_t)s * RTOT + rowbase;
#pragma unroll
  for (int r = 0; r < 4; ++r) {
    size_t pra = prow0 + q0 + g * 4 + r;
    pO[pra * HDIM + c]      = oa0[r];
    pO[pra * HDIM + 16 + c] = oa1[r];
    size_t prb = prow0 + q1 + g * 4 + r;
    pO[prb * HDIM + c]      = ob0[r];
    pO[prb * HDIM + 16 + c] = ob1[r];
    if (c == 0) { pL[pra] = la[r]; pL[prb] = lb[r]; }
  }
}

// ------- fused merge + proj GEMM: phase1 merge pO->LDS split-bf16 A, phase2 MFMA -------
#define ALD 264   // LDS A row stride in u16 (264*2=528B, 16B-aligned rows)
__launch_bounds__(256)
__global__ void gemm_proj_fused(const float* __restrict__ pO, const float* __restrict__ pL,
                                const ushort* __restrict__ Bh_, const ushort* __restrict__ Bl_,
                                const float* __restrict__ bias, float* __restrict__ C) {
  __shared__ __align__(16) ushort Ahs[64 * ALD];
  __shared__ __align__(16) ushort Als[64 * ALD];
  int tid = threadIdx.x;
  int m0 = blockIdx.x * 64;
  int b = (m0 >= NSEQ) ? 1 : 0;
  int nb = m0 - b * NSEQ;

  // ---- phase 1: merge splits, normalize, split-bf16, stage to LDS ----
  {
    int r = tid >> 2;            // local row 0..63
    int q = tid & 3;             // 8-chan group within head
    int n = nb + r;
#pragma unroll
    for (int h = 0; h < NHEADS; ++h) {
      size_t bhn = (size_t)(b * NHEADS + h) * NSEQ + n;
      float L = 0.f;
#pragma unroll
      for (int sp = 0; sp < SPLITS; ++sp) L += pL[(size_t)sp * RTOT + bhn];
      float inv = 1.f / L;
      float a[8] = {0.f, 0.f, 0.f, 0.f, 0.f, 0.f, 0.f, 0.f};
#pragma unroll
      for (int sp = 0; sp < SPLITS; ++sp) {
        const float* src = &pO[((size_t)sp * RTOT + bhn) * HDIM + q * 8];
        float4 v0 = *(const float4*)&src[0];
        float4 v1 = *(const float4*)&src[4];
        a[0] += v0.x; a[1] += v0.y; a[2] += v0.z; a[3] += v0.w;
        a[4] += v1.x; a[5] += v1.y; a[6] += v1.z; a[7] += v1.w;
      }
      ushort hi8[8], lo8[8];
#pragma unroll
      for (int i = 0; i < 8; ++i) {
        float v = a[i] * inv;
        ushort hh = f2bf(v);
        hi8[i] = hh;
        lo8[i] = f2bf(v - bf2f(hh));
      }
      int k = h * 32 + q * 8;
      *(int4*)&Ahs[r * ALD + k] = *(int4*)hi8;
      *(int4*)&Als[r * ALD + k] = *(int4*)lo8;
    }
  }
  __syncthreads();

  // ---- phase 2: C[64 x 256] = A @ Wp^T + bias ----
  int lane = tid & 63, w = tid >> 6;
  int g = lane >> 4, c = lane & 15;
  int n0 = w * 64;
  f32x4 acc[4][4] = {};
  for (int k0 = 0; k0 < DIMC; k0 += 32) {
    short8 bfh[4], bfl[4];
#pragma unroll
    for (int nt = 0; nt < 4; ++nt) {
      bfh[nt] = *(const short8*)&Bh_[(size_t)(n0 + nt * 16 + c) * DIMC + k0 + g * 8];
      bfl[nt] = *(const short8*)&Bl_[(size_t)(n0 + nt * 16 + c) * DIMC + k0 + g * 8];
    }
#pragma unroll
    for (int mt = 0; mt < 4; ++mt) {
      short8 ah = *(const short8*)&Ahs[(mt * 16 + c) * ALD + k0 + g * 8];
      short8 al = *(const short8*)&Als[(mt * 16 + c) * ALD + k0 + g * 8];
#pragma unroll
      for (int nt = 0; nt < 4; ++nt) {
        acc[mt][nt] = MFMA16(ah, bfh[nt], acc[mt][nt]);
        acc[mt][nt] = MFMA16(al, bfh[nt], acc[mt][nt]);
        acc[mt][nt] = MFMA16(ah, bfl[nt], acc[mt][nt]);
      }
    }
  }
#pragma unroll
  for (int nt = 0; nt < 4; ++nt) {
    float bv = bias[n0 + nt * 16 + c];
#pragma unroll
    for (int mt = 0; mt < 4; ++mt)
#pragma unroll
      for (int r = 0; r < 4; ++r)
        C[(size_t)(m0 + mt * 16 + g * 4 + r) * DIMC + n0 + nt * 16 + c] = acc[mt][nt][r] + bv;
  }
}

extern "C" void kernel_launch(void* const* d_in, const int* in_sizes, int n_in,
                              void* d_out, int out_size, void* d_ws, size_t ws_size,
                              hipStream_t stream) {
  const float* x    = (const float*)d_in[0];
  const int*   idx  = (const int*)d_in[1];
  const float* tbl  = (const float*)d_in[2];
  const float* sls  = (const float*)d_in[3];
  const float* Wqkv = (const float*)d_in[5];
  const float* bqkv = (const float*)d_in[6];
  const float* temp = (const float*)d_in[7];
  const float* qe   = (const float*)d_in[8];
  const float* Wp   = (const float*)d_in[9];
  const float* bp   = (const float*)d_in[10];
  const float* W1   = (const float*)d_in[11];
  const float* b1   = (const float*)d_in[12];
  const float* W2   = (const float*)d_in[13];
  const float* b2   = (const float*)d_in[14];

  float* ws   = (float*)d_ws;
  float* pO   = ws;                            // 4,718,592 f
  float* pL   = pO + (size_t)SPLITS * RTOT * HDIM;   // 147,456 f
  unsigned* idxP = (unsigned*)(pL + (size_t)SPLITS * RTOT);
  ushort* u   = (ushort*)(idxP + IDXP_ELEMS);
  ushort* qhi = u;                u += (size_t)RTOT * HDIM;
  ushort* qlo = u;                u += (size_t)RTOT * HDIM;
  ushort* khi = u;                u += (size_t)RTOT * HDIM;
  ushort* klo = u;                u += (size_t)RTOT * HDIM;
  ushort* vT  = u;                u += (size_t)RTOT * HDIM;
  ushort* xh  = u;                u += NX;
  ushort* xl  = u;                u += NX;
  ushort* wqh = u;                u += NWQ;
  ushort* wql = u;                u += NWQ;
  ushort* wph = u;                u += NWP;
  ushort* wpl = u;                u += NWP;
  ushort* tabBf = u;              u += 73728;   // 8*TABP = 72,320 + slack
  float* out  = (float*)d_out;

  setup_kernel<<<dim3(CPB_BLOCKS + SPLITX4_BLOCKS + IDXP4_BLOCKS), dim3(256), 0, stream>>>(
      x, Wqkv, Wp, idx, tbl, W1, b1, W2, b2,
      xh, xl, wqh, wql, wph, wpl, idxP, tabBf);
  gemm_qkv<<<dim3(12, 72), dim3(256), 0, stream>>>(
      xh, xl, wqh, wql, bqkv, temp, sls, qe, qhi, qlo, khi, klo, vT);
  attn_kernel<<<dim3(NSEQ / 128, BB * NHEADS * SPLITS), dim3(256), 0, stream>>>(
      qhi, qlo, khi, klo, vT, tabBf, idxP, pO, pL);
  gemm_proj_fused<<<dim3((BB * NSEQ) / 64), dim3(256), 0, stream>>>(
      pO, pL, wph, wpl, bp, out);
}